// Round 7
// baseline (387.480 us; speedup 1.0000x reference)
//
#include <hip/hip_runtime.h>
#include <hip/hip_bf16.h>
#include <stdint.h>

#define S_LEN 2048
#define HD 128
#define QBLK 128
#define KVBLK 64
#define TPB 512
#define NBH 32
#define NKT (S_LEN / KVBLK)      // 32 kv tiles
#define KIMG_TILE 16384          // 64x128 bf16 LDS image bytes

typedef __attribute__((ext_vector_type(8))) short bf16x8;
typedef __attribute__((ext_vector_type(4))) float f32x4;

__device__ __forceinline__ unsigned short f2b(float f) {
  union { float fv; unsigned u; } v; v.fv = f;
  unsigned r = v.u + 0x7fffu + ((v.u >> 16) & 1u);
  return (unsigned short)(r >> 16);
}
__device__ __forceinline__ float b2f(unsigned short h) {
  union { unsigned u; float fv; } v; v.u = ((unsigned)h) << 16; return v.fv;
}

typedef __attribute__((address_space(3))) uint32_t lds_u32_t;
typedef __attribute__((address_space(1))) const uint32_t glb_u32_t;
__device__ __forceinline__ void gll16(const void* g, void* l) {
  __builtin_amdgcn_global_load_lds((glb_u32_t*)g, (lds_u32_t*)l, 16, 0, 0);
}

// ============================================================================
// Pre-pass: K -> (hi,lo) bf16 swizzled LDS-images; V -> Vt[d][kv] bf16 image.
// ============================================================================
__global__ __launch_bounds__(256) void prep_kv(
    const float* __restrict__ Kg, const float* __restrict__ Vg,
    char* __restrict__ KhiI, char* __restrict__ KloI, char* __restrict__ VtI) {
  __shared__ __align__(16) char vlds[64 * 528];
  const int t = threadIdx.x;
  const int bh = blockIdx.x >> 5;
  const int kt = blockIdx.x & 31;
  const size_t base = ((size_t)bh * S_LEN + (size_t)kt * KVBLK) * HD;
  const size_t tbase = ((size_t)bh * NKT + kt) * KIMG_TILE;

  {
    const int row = t >> 2;
    const int c4 = (t & 3) * 32;
    const float* src = Kg + base + (size_t)row * HD + c4;
#pragma unroll
    for (int j8 = 0; j8 < 4; ++j8) {
      float4 a = *(const float4*)(src + j8 * 8);
      float4 b = *(const float4*)(src + j8 * 8 + 4);
      float vs[8] = {a.x, a.y, a.z, a.w, b.x, b.y, b.z, b.w};
      bf16x8 hi, lo;
#pragma unroll
      for (int j = 0; j < 8; ++j) {
        unsigned short h = f2b(vs[j]);
        hi[j] = (short)h;
        lo[j] = (short)f2b(vs[j] - b2f(h));
      }
      int off = (row * 256 + (c4 + j8 * 8) * 2) ^ ((row & 7) << 4);
      *(bf16x8*)(KhiI + tbase + off) = hi;
      *(bf16x8*)(KloI + tbase + off) = lo;
    }
  }

#pragma unroll
  for (int it = 0; it < 8; ++it) {
    int idx = it * 256 + t;
    int row = idx >> 5;
    int cb = (idx & 31) * 16;
    float4 v = *(const float4*)((const char*)(Vg + base + (size_t)row * HD) + cb);
    *(float4*)(vlds + row * 528 + cb) = v;
  }
  __syncthreads();
  {
    const int d = t & 127;
    const int kvb = (t >> 7) * 32;
#pragma unroll
    for (int jj = 0; jj < 4; ++jj) {
      bf16x8 o;
#pragma unroll
      for (int j = 0; j < 8; ++j) {
        int kv = kvb + jj * 8 + j;
        float f = *(const float*)(vlds + kv * 528 + d * 4);
        o[j] = (short)f2b(f);
      }
      int off = (d * 128 + (kvb + jj * 8) * 2) ^ ((d & 7) << 4);
      *(bf16x8*)(VtI + tbase + off) = o;
    }
  }
}

// ============================================================================
// Pipelined attention: double-buffered K/V images, counted vmcnt, raw barriers.
// LDS: buf0{KsmH,KsmL,Vsm} 48K | buf1 48K | Psm 8x2K = 112KB -> 1 block/CU.
// ============================================================================
#define BUFB 49152
#define SMEMF3 (2 * BUFB + 8 * 2048)

__global__ __launch_bounds__(TPB, 2) void attn_fwd3(
    const char* __restrict__ KhiI, const char* __restrict__ KloI,
    const char* __restrict__ VtI, const float* __restrict__ Qg,
    const int* __restrict__ Mg, float* __restrict__ Og) {
  __shared__ __align__(16) char smem[SMEMF3];
  char* Psm = smem + 2 * BUFB;

  const int tid = threadIdx.x;
  const int wave = tid >> 6;
  const int lane = tid & 63;
  const int lm = lane & 15;
  const int lg = lane >> 4;

  const int bh = blockIdx.x;
  const int q0 = blockIdx.y * QBLK;
  const int qrow0 = q0 + wave * 16;
  const size_t base = (size_t)bh * S_LEN * HD;
  const float* Qb = Qg + base;

  // ---- Q fragments: hi/lo bf16 split, 1/T folded ----
  bf16x8 qhi[4], qlo[4];
#pragma unroll
  for (int c = 0; c < 4; ++c) {
    const float* src = Qb + (size_t)(qrow0 + lm) * HD + c * 32 + lg * 8;
    float4 a = *(const float4*)src;
    float4 b = *(const float4*)(src + 4);
    float qs[8] = {a.x, a.y, a.z, a.w, b.x, b.y, b.z, b.w};
    bf16x8 fh, fl;
#pragma unroll
    for (int j = 0; j < 8; ++j) {
      float v = qs[j] * 1.25f;
      unsigned short h = f2b(v);
      fh[j] = (short)h;
      fl[j] = (short)f2b(v - b2f(h));
    }
    qhi[c] = fh;
    qlo[c] = fl;
  }

  f32x4 acc[8];
#pragma unroll
  for (int i = 0; i < 8; ++i) acc[i] = (f32x4){0.f, 0.f, 0.f, 0.f};
  float mrun[4] = {-1e30f, -1e30f, -1e30f, -1e30f};
  float lrun[4] = {0.f, 0.f, 0.f, 0.f};

  char* Pw = Psm + wave * 2048;
  const int wo = wave * 2048 + lane * 16;

  // prologue: stage tile 0 into buf0; prefetch mask tile 0
  {
    const size_t tb = (size_t)bh * NKT * KIMG_TILE;
    char* B = smem;
    gll16(KhiI + tb + wo,        B + wave * 2048);
    gll16(KhiI + tb + wo + 1024, B + wave * 2048 + 1024);
    gll16(KloI + tb + wo,        B + 16384 + wave * 2048);
    gll16(KloI + tb + wo + 1024, B + 16384 + wave * 2048 + 1024);
    gll16(VtI + tb + wo,         B + 32768 + wave * 2048);
    gll16(VtI + tb + wo + 1024,  B + 32768 + wave * 2048 + 1024);
  }
  int mk[4][4], mkn[4][4];
#pragma unroll
  for (int r = 0; r < 4; ++r) {
    const int* mr = Mg + (size_t)(qrow0 + lg * 4 + r) * S_LEN + lm;
#pragma unroll
    for (int st = 0; st < 4; ++st) mk[r][st] = mr[st * 16];
  }

  for (int kt = 0; kt < NKT; ++kt) {
    const int cur = kt & 1;
    char* Bc = smem + cur * BUFB;

    if (kt + 1 < NKT) {
      // issue next tile's stage into the other buffer (freed by last barrier)
      const size_t tb = ((size_t)bh * NKT + (kt + 1)) * KIMG_TILE;
      char* Bn = smem + (cur ^ 1) * BUFB;
      gll16(KhiI + tb + wo,        Bn + wave * 2048);
      gll16(KhiI + tb + wo + 1024, Bn + wave * 2048 + 1024);
      gll16(KloI + tb + wo,        Bn + 16384 + wave * 2048);
      gll16(KloI + tb + wo + 1024, Bn + 16384 + wave * 2048 + 1024);
      gll16(VtI + tb + wo,         Bn + 32768 + wave * 2048);
      gll16(VtI + tb + wo + 1024,  Bn + 32768 + wave * 2048 + 1024);
      // prefetch next mask tile
      const int kv1 = (kt + 1) * KVBLK;
#pragma unroll
      for (int r = 0; r < 4; ++r) {
        const int* mr = Mg + (size_t)(qrow0 + lg * 4 + r) * S_LEN + kv1 + lm;
#pragma unroll
        for (int st = 0; st < 4; ++st) mkn[r][st] = mr[st * 16];
      }
      // 22 newer VMEM ops (6 gll16 + 16 mask) -> current tile's loads landed
      asm volatile("s_waitcnt vmcnt(22)" ::: "memory");
    } else {
      asm volatile("s_waitcnt vmcnt(0)" ::: "memory");
    }
    __builtin_amdgcn_sched_barrier(0);
    __builtin_amdgcn_s_barrier();   // all waves' stage-writes for tile kt landed

    // ---- QK^T: hi*hi + lo*hi + hi*lo ----
    f32x4 sf[4];
#pragma unroll
    for (int st = 0; st < 4; ++st) {
      f32x4 c = (f32x4){0.f, 0.f, 0.f, 0.f};
#pragma unroll
      for (int ch = 0; ch < 4; ++ch) {
        int krow = st * 16 + lm;
        int byo = (krow * 256 + ch * 64 + lg * 16) ^ ((krow & 7) << 4);
        bf16x8 khi = *(const bf16x8*)(Bc + byo);
        bf16x8 klo = *(const bf16x8*)(Bc + 16384 + byo);
        c = __builtin_amdgcn_mfma_f32_16x16x32_bf16(qhi[ch], khi, c, 0, 0, 0);
        c = __builtin_amdgcn_mfma_f32_16x16x32_bf16(qlo[ch], khi, c, 0, 0, 0);
        c = __builtin_amdgcn_mfma_f32_16x16x32_bf16(qhi[ch], klo, c, 0, 0, 0);
      }
      sf[st] = c;
    }

    // ---- mask + online softmax ----
    float pv[4][4];
#pragma unroll
    for (int r = 0; r < 4; ++r) {
      float sc[4];
      float mx = -1e30f;
#pragma unroll
      for (int st = 0; st < 4; ++st) {
        float s = sf[st][r];
        sc[st] = mk[r][st] ? s : -1e-9f;
        mx = fmaxf(mx, sc[st]);
      }
      mx = fmaxf(mx, __shfl_xor(mx, 1));
      mx = fmaxf(mx, __shfl_xor(mx, 2));
      mx = fmaxf(mx, __shfl_xor(mx, 4));
      mx = fmaxf(mx, __shfl_xor(mx, 8));
      float mnew = fmaxf(mrun[r], mx);
      float scale = __expf(mrun[r] - mnew);
      float ps = 0.f;
#pragma unroll
      for (int st = 0; st < 4; ++st) {
        float p = __expf(sc[st] - mnew);
        pv[st][r] = p;
        ps += p;
      }
      ps += __shfl_xor(ps, 1);
      ps += __shfl_xor(ps, 2);
      ps += __shfl_xor(ps, 4);
      ps += __shfl_xor(ps, 8);
      lrun[r] = lrun[r] * scale + ps;
      mrun[r] = mnew;
#pragma unroll
      for (int dt = 0; dt < 8; ++dt) acc[dt][r] *= scale;
    }

    // ---- P -> wave-private LDS, [16][64] bf16 swizzled ----
#pragma unroll
    for (int st = 0; st < 4; ++st) {
#pragma unroll
      for (int r = 0; r < 4; ++r) {
        int row = lg * 4 + r;
        int byo = (row * 128 + (st * 16 + lm) * 2) ^ ((row & 7) << 4);
        *(unsigned short*)(Pw + byo) = f2b(pv[st][r]);
      }
    }
    asm volatile("s_waitcnt lgkmcnt(0)" ::: "memory");
    __builtin_amdgcn_sched_barrier(0);

    // ---- PV: O(16x128) += P(16x64) * V(64x128) ----
#pragma unroll
    for (int kk = 0; kk < 2; ++kk) {
      bf16x8 pa = *(const bf16x8*)(Pw + ((lm * 128 + kk * 64 + lg * 16) ^ ((lm & 7) << 4)));
#pragma unroll
      for (int dt = 0; dt < 8; ++dt) {
        int vrow = dt * 16 + lm;
        bf16x8 vb = *(const bf16x8*)(Bc + 32768 + ((vrow * 128 + kk * 64 + lg * 16) ^ ((lm & 7) << 4)));
        acc[dt] = __builtin_amdgcn_mfma_f32_16x16x32_bf16(pa, vb, acc[dt], 0, 0, 0);
      }
    }

    __builtin_amdgcn_sched_barrier(0);
    __builtin_amdgcn_s_barrier();   // all waves done with buf[cur] before it's re-staged

    if (kt + 1 < NKT) {
#pragma unroll
      for (int r = 0; r < 4; ++r)
#pragma unroll
        for (int st = 0; st < 4; ++st) mk[r][st] = mkn[r][st];
    }
  }

  // ---- epilogue ----
  float invl[4];
#pragma unroll
  for (int r = 0; r < 4; ++r) invl[r] = 1.f / lrun[r];
  float* ob = Og + base;
#pragma unroll
  for (int dt = 0; dt < 8; ++dt) {
#pragma unroll
    for (int r = 0; r < 4; ++r) {
      ob[(size_t)(qrow0 + lg * 4 + r) * HD + dt * 16 + lm] = acc[dt][r] * invl[r];
    }
  }
}

// ============================================================================
// Fallback (Round-3 verified kernel) if ws too small for images.
// ============================================================================
#define KSM_BYTES (KVBLK * HD * 2)
#define VSM_BYTES (HD * 72 * 2)
#define PSM_PER_WAVE (16 * 72 * 2)
#define SMEM_BYTES (2 * KSM_BYTES + VSM_BYTES + 8 * PSM_PER_WAVE)

__global__ __launch_bounds__(TPB, 2) void attn_fwd(
    const float* __restrict__ Kg, const float* __restrict__ Vg,
    const float* __restrict__ Qg, const int* __restrict__ Mg,
    float* __restrict__ Og) {
  __shared__ __align__(16) char smem[SMEM_BYTES];
  char* KsmH = smem;
  char* KsmL = smem + KSM_BYTES;
  char* Vsm = smem + 2 * KSM_BYTES;
  char* Psm = smem + 2 * KSM_BYTES + VSM_BYTES;

  const int tid = threadIdx.x;
  const int wave = tid >> 6;
  const int lane = tid & 63;
  const int lm = lane & 15;
  const int lg = lane >> 4;

  const int bh = blockIdx.x;
  const int q0 = blockIdx.y * QBLK;
  const int qrow0 = q0 + wave * 16;

  const size_t base = (size_t)bh * S_LEN * HD;
  const float* Kb = Kg + base;
  const float* Vb = Vg + base;
  const float* Qb = Qg + base;

  bf16x8 qhi[4], qlo[4];
#pragma unroll
  for (int c = 0; c < 4; ++c) {
    const float* src = Qb + (size_t)(qrow0 + lm) * HD + c * 32 + lg * 8;
    float4 a = *(const float4*)src;
    float4 b = *(const float4*)(src + 4);
    float qs[8] = {a.x, a.y, a.z, a.w, b.x, b.y, b.z, b.w};
    bf16x8 fh, fl;
#pragma unroll
    for (int j = 0; j < 8; ++j) {
      float v = qs[j] * 1.25f;
      unsigned short h = f2b(v);
      fh[j] = (short)h;
      fl[j] = (short)f2b(v - b2f(h));
    }
    qhi[c] = fh;
    qlo[c] = fl;
  }

  f32x4 acc[8];
#pragma unroll
  for (int i = 0; i < 8; ++i) acc[i] = (f32x4){0.f, 0.f, 0.f, 0.f};
  float mrun[4] = {-1e30f, -1e30f, -1e30f, -1e30f};
  float lrun[4] = {0.f, 0.f, 0.f, 0.f};

  char* Pw = Psm + wave * PSM_PER_WAVE;

  for (int kt = 0; kt < S_LEN / KVBLK; ++kt) {
    const int kv0 = kt * KVBLK;
    int mk[4][4];
#pragma unroll
    for (int r = 0; r < 4; ++r) {
      const int* mr = Mg + (size_t)(qrow0 + lg * 4 + r) * S_LEN + kv0 + lm;
#pragma unroll
      for (int st = 0; st < 4; ++st) mk[r][st] = mr[st * 16];
    }
    __syncthreads();
#pragma unroll
    for (int it = 0; it < 4; ++it) {
      int row = it * 16 + (tid >> 5);
      int col = (tid & 31) * 4;
      float4 v = *(const float4*)(Kb + (size_t)(kv0 + row) * HD + col);
      ushort4 hi, lo;
      hi.x = f2b(v.x); lo.x = f2b(v.x - b2f(hi.x));
      hi.y = f2b(v.y); lo.y = f2b(v.y - b2f(hi.y));
      hi.z = f2b(v.z); lo.z = f2b(v.z - b2f(hi.z));
      hi.w = f2b(v.w); lo.w = f2b(v.w - b2f(hi.w));
      int byo = (row * 256 + col * 2) ^ ((row & 7) << 4);
      *(ushort4*)(KsmH + byo) = hi;
      *(ushort4*)(KsmL + byo) = lo;
    }
    {
      int d = tid & 127;
      int kvh = (tid >> 7) * 16;
      const float* vc = Vb + (size_t)kv0 * HD + d;
#pragma unroll
      for (int j = 0; j < 4; ++j) {
        int kvb = kvh + j * 4;
        ushort4 h = make_ushort4(f2b(vc[(size_t)(kvb + 0) * HD]),
                                 f2b(vc[(size_t)(kvb + 1) * HD]),
                                 f2b(vc[(size_t)(kvb + 2) * HD]),
                                 f2b(vc[(size_t)(kvb + 3) * HD]));
        *(ushort4*)(Vsm + d * 144 + kvb * 2) = h;
      }
    }
    __syncthreads();

    f32x4 sf[4];
#pragma unroll
    for (int st = 0; st < 4; ++st) {
      f32x4 c = (f32x4){0.f, 0.f, 0.f, 0.f};
#pragma unroll
      for (int ch = 0; ch < 4; ++ch) {
        int krow = st * 16 + lm;
        int byo = (krow * 256 + (ch * 32 + lg * 8) * 2) ^ ((krow & 7) << 4);
        bf16x8 khi = *(const bf16x8*)(KsmH + byo);
        bf16x8 klo = *(const bf16x8*)(KsmL + byo);
        c = __builtin_amdgcn_mfma_f32_16x16x32_bf16(qhi[ch], khi, c, 0, 0, 0);
        c = __builtin_amdgcn_mfma_f32_16x16x32_bf16(qlo[ch], khi, c, 0, 0, 0);
        c = __builtin_amdgcn_mfma_f32_16x16x32_bf16(qhi[ch], klo, c, 0, 0, 0);
      }
      sf[st] = c;
    }

    float pv[4][4];
#pragma unroll
    for (int r = 0; r < 4; ++r) {
      float sc[4];
      float mx = -1e30f;
#pragma unroll
      for (int st = 0; st < 4; ++st) {
        float s = sf[st][r];
        sc[st] = mk[r][st] ? s : -1e-9f;
        mx = fmaxf(mx, sc[st]);
      }
      mx = fmaxf(mx, __shfl_xor(mx, 1));
      mx = fmaxf(mx, __shfl_xor(mx, 2));
      mx = fmaxf(mx, __shfl_xor(mx, 4));
      mx = fmaxf(mx, __shfl_xor(mx, 8));
      float mnew = fmaxf(mrun[r], mx);
      float scale = __expf(mrun[r] - mnew);
      float ps = 0.f;
#pragma unroll
      for (int st = 0; st < 4; ++st) {
        float p = __expf(sc[st] - mnew);
        pv[st][r] = p;
        ps += p;
      }
      ps += __shfl_xor(ps, 1);
      ps += __shfl_xor(ps, 2);
      ps += __shfl_xor(ps, 4);
      ps += __shfl_xor(ps, 8);
      lrun[r] = lrun[r] * scale + ps;
      mrun[r] = mnew;
#pragma unroll
      for (int dt = 0; dt < 8; ++dt) acc[dt][r] *= scale;
    }

#pragma unroll
    for (int st = 0; st < 4; ++st) {
#pragma unroll
      for (int r = 0; r < 4; ++r) {
        int row = lg * 4 + r;
        int col = st * 16 + lm;
        *(unsigned short*)(Pw + row * 144 + col * 2) = f2b(pv[st][r]);
      }
    }
    asm volatile("s_waitcnt lgkmcnt(0)" ::: "memory");
    __builtin_amdgcn_sched_barrier(0);

#pragma unroll
    for (int kk = 0; kk < 2; ++kk) {
      bf16x8 pa = *(const bf16x8*)(Pw + lm * 144 + kk * 64 + lg * 16);
#pragma unroll
      for (int dt = 0; dt < 8; ++dt) {
        bf16x8 vb = *(const bf16x8*)(Vsm + (dt * 16 + lm) * 144 + kk * 64 + lg * 16);
        acc[dt] = __builtin_amdgcn_mfma_f32_16x16x32_bf16(pa, vb, acc[dt], 0, 0, 0);
      }
    }
  }

  float invl[4];
#pragma unroll
  for (int r = 0; r < 4; ++r) invl[r] = 1.f / lrun[r];
  float* ob = Og + base;
#pragma unroll
  for (int dt = 0; dt < 8; ++dt) {
#pragma unroll
    for (int r = 0; r < 4; ++r) {
      ob[(size_t)(qrow0 + lg * 4 + r) * HD + dt * 16 + lm] = acc[dt][r] * invl[r];
    }
  }
}

extern "C" void kernel_launch(void* const* d_in, const int* in_sizes, int n_in,
                              void* d_out, int out_size, void* d_ws, size_t ws_size,
                              hipStream_t stream) {
  const float* key   = (const float*)d_in[0];
  const float* value = (const float*)d_in[1];
  const float* query = (const float*)d_in[2];
  const int*   mask  = (const int*)d_in[3];
  float* out = (float*)d_out;

  const size_t PLANE = (size_t)NBH * NKT * KIMG_TILE;  // 16MB
  if (ws_size >= 3 * PLANE) {
    char* khi = (char*)d_ws;
    char* klo = khi + PLANE;
    char* vt  = klo + PLANE;
    prep_kv<<<dim3(NBH * NKT), dim3(256), 0, stream>>>(key, value, khi, klo, vt);
    attn_fwd3<<<dim3(NBH, S_LEN / QBLK), dim3(TPB), 0, stream>>>(khi, klo, vt, query, mask, out);
  } else {
    attn_fwd<<<dim3(NBH, S_LEN / QBLK), dim3(TPB), 0, stream>>>(key, value, query, mask, out);
  }
}

// Round 8
// 337.553 us; speedup vs baseline: 1.1479x; 1.1479x over previous
//
#include <hip/hip_runtime.h>
#include <hip/hip_bf16.h>
#include <stdint.h>

#define S_LEN 2048
#define HD 128
#define QBLK 128
#define KVBLK 64
#define TPB 512
#define NBH 32
#define NKT (S_LEN / KVBLK)      // 32 kv tiles
#define KIMG_TILE 16384          // 64x128 f16 LDS image bytes

typedef __attribute__((ext_vector_type(8))) _Float16 f16x8;
typedef __attribute__((ext_vector_type(8))) short s16x8;
typedef __attribute__((ext_vector_type(4))) float f32x4;

__device__ __forceinline__ short f2h(float f) {
  _Float16 h = (_Float16)f;           // round-to-nearest-even
  return __builtin_bit_cast(short, h);
}
__device__ __forceinline__ unsigned short f2b(float f) {
  union { float fv; unsigned u; } v; v.fv = f;
  unsigned r = v.u + 0x7fffu + ((v.u >> 16) & 1u);
  return (unsigned short)(r >> 16);
}
__device__ __forceinline__ float b2f(unsigned short h) {
  union { unsigned u; float fv; } v; v.u = ((unsigned)h) << 16; return v.fv;
}

typedef __attribute__((address_space(3))) uint32_t lds_u32_t;
typedef __attribute__((address_space(1))) const uint32_t glb_u32_t;
__device__ __forceinline__ void gll16(const void* g, void* l) {
  __builtin_amdgcn_global_load_lds((glb_u32_t*)g, (lds_u32_t*)l, 16, 0, 0);
}

// ============================================================================
// Pre-pass: K -> f16 swizzled LDS-image; V -> Vt[d][kv] f16 image.
// Image byte layout == LDS byte layout (swizzle pre-baked), staging is linear.
// ============================================================================
__global__ __launch_bounds__(256) void prep_kv(
    const float* __restrict__ Kg, const float* __restrict__ Vg,
    char* __restrict__ KfI, char* __restrict__ VtI) {
  __shared__ __align__(16) char vlds[64 * 528];
  const int t = threadIdx.x;
  const int bh = blockIdx.x >> 5;
  const int kt = blockIdx.x & 31;
  const size_t base = ((size_t)bh * S_LEN + (size_t)kt * KVBLK) * HD;
  const size_t tbase = ((size_t)bh * NKT + kt) * KIMG_TILE;

  // ---- K tile: 64 rows x 128 cols -> f16, XOR-swizzled ----
  {
    const int row = t >> 2;
    const int c4 = (t & 3) * 32;
    const float* src = Kg + base + (size_t)row * HD + c4;
#pragma unroll
    for (int j8 = 0; j8 < 4; ++j8) {
      float4 a = *(const float4*)(src + j8 * 8);
      float4 b = *(const float4*)(src + j8 * 8 + 4);
      float vs[8] = {a.x, a.y, a.z, a.w, b.x, b.y, b.z, b.w};
      s16x8 h;
#pragma unroll
      for (int j = 0; j < 8; ++j) h[j] = f2h(vs[j]);
      int off = (row * 256 + (c4 + j8 * 8) * 2) ^ ((row & 7) << 4);
      *(s16x8*)(KfI + tbase + off) = h;
    }
  }

  // ---- V tile: coalesced load -> LDS (padded) -> transposed f16 image ----
#pragma unroll
  for (int it = 0; it < 8; ++it) {
    int idx = it * 256 + t;
    int row = idx >> 5;
    int cb = (idx & 31) * 16;
    float4 v = *(const float4*)((const char*)(Vg + base + (size_t)row * HD) + cb);
    *(float4*)(vlds + row * 528 + cb) = v;
  }
  __syncthreads();
  {
    const int d = t & 127;
    const int kvb = (t >> 7) * 32;
#pragma unroll
    for (int jj = 0; jj < 4; ++jj) {
      s16x8 o;
#pragma unroll
      for (int j = 0; j < 8; ++j) {
        int kv = kvb + jj * 8 + j;
        float f = *(const float*)(vlds + kv * 528 + d * 4);
        o[j] = f2h(f);
      }
      int off = (d * 128 + (kvb + jj * 8) * 2) ^ ((d & 7) << 4);
      *(s16x8*)(VtI + tbase + off) = o;
    }
  }
}

// ============================================================================
// f16 attention: double-buffered images, counted vmcnt, defer-rescale, setprio.
// LDS: 2 x {Kf 16K | Vt 16K} | Psm 8x2K = 80KB -> 2 blocks/CU.
// ============================================================================
#define BUFB 32768
#define SMEMF4 (2 * BUFB + 8 * 2048)

__global__ __launch_bounds__(TPB, 2) void attn_fwd4(
    const char* __restrict__ KfI, const char* __restrict__ VtI,
    const float* __restrict__ Qg, const int* __restrict__ Mg,
    float* __restrict__ Og) {
  __shared__ __align__(16) char smem[SMEMF4];
  char* Psm = smem + 2 * BUFB;

  const int tid = threadIdx.x;
  const int wave = tid >> 6;
  const int lane = tid & 63;
  const int lm = lane & 15;
  const int lg = lane >> 4;

  const int bh = blockIdx.x;
  const int q0 = blockIdx.y * QBLK;
  const int qrow0 = q0 + wave * 16;
  const size_t base = (size_t)bh * S_LEN * HD;
  const float* Qb = Qg + base;

  // ---- Q fragments: f16, 1/T = 1.25 folded ----
  f16x8 qf[4];
#pragma unroll
  for (int c = 0; c < 4; ++c) {
    const float* src = Qb + (size_t)(qrow0 + lm) * HD + c * 32 + lg * 8;
    float4 a = *(const float4*)src;
    float4 b = *(const float4*)(src + 4);
    float qs[8] = {a.x, a.y, a.z, a.w, b.x, b.y, b.z, b.w};
    f16x8 f;
#pragma unroll
    for (int j = 0; j < 8; ++j) f[j] = (_Float16)(qs[j] * 1.25f);
    qf[c] = f;
  }

  f32x4 acc[8];
#pragma unroll
  for (int i = 0; i < 8; ++i) acc[i] = (f32x4){0.f, 0.f, 0.f, 0.f};
  float mrun[4] = {-1e30f, -1e30f, -1e30f, -1e30f};
  float lrun[4] = {0.f, 0.f, 0.f, 0.f};

  char* Pw = Psm + wave * 2048;
  const int wo = wave * 2048 + lane * 16;

  // prologue: stage tile 0 into buf0 (4 gll16) + mask tile 0 (16 loads)
  {
    const size_t tb = (size_t)bh * NKT * KIMG_TILE;
    char* B = smem;
    gll16(KfI + tb + wo,         B + wave * 2048);
    gll16(KfI + tb + wo + 1024,  B + wave * 2048 + 1024);
    gll16(VtI + tb + wo,         B + 16384 + wave * 2048);
    gll16(VtI + tb + wo + 1024,  B + 16384 + wave * 2048 + 1024);
  }
  int mk[4][4], mkn[4][4];
#pragma unroll
  for (int r = 0; r < 4; ++r) {
    const int* mr = Mg + (size_t)(qrow0 + lg * 4 + r) * S_LEN + lm;
#pragma unroll
    for (int st = 0; st < 4; ++st) mk[r][st] = mr[st * 16];
  }

  for (int kt = 0; kt < NKT; ++kt) {
    const int cur = kt & 1;
    char* Bc = smem + cur * BUFB;

    if (kt + 1 < NKT) {
      const size_t tb = ((size_t)bh * NKT + (kt + 1)) * KIMG_TILE;
      char* Bn = smem + (cur ^ 1) * BUFB;
      gll16(KfI + tb + wo,         Bn + wave * 2048);
      gll16(KfI + tb + wo + 1024,  Bn + wave * 2048 + 1024);
      gll16(VtI + tb + wo,         Bn + 16384 + wave * 2048);
      gll16(VtI + tb + wo + 1024,  Bn + 16384 + wave * 2048 + 1024);
      const int kv1 = (kt + 1) * KVBLK;
#pragma unroll
      for (int r = 0; r < 4; ++r) {
        const int* mr = Mg + (size_t)(qrow0 + lg * 4 + r) * S_LEN + kv1 + lm;
#pragma unroll
        for (int st = 0; st < 4; ++st) mkn[r][st] = mr[st * 16];
      }
      // 20 newer VMEM ops (4 gll16 + 16 mask) -> tile kt's staging landed
      asm volatile("s_waitcnt vmcnt(20)" ::: "memory");
    } else {
      asm volatile("s_waitcnt vmcnt(0)" ::: "memory");
    }
    __builtin_amdgcn_sched_barrier(0);
    __builtin_amdgcn_s_barrier();   // all waves' stage-writes for tile kt landed

    // ---- QK^T: single f16 product ----
    __builtin_amdgcn_s_setprio(1);
    f32x4 sf[4];
#pragma unroll
    for (int st = 0; st < 4; ++st) {
      f32x4 c = (f32x4){0.f, 0.f, 0.f, 0.f};
#pragma unroll
      for (int ch = 0; ch < 4; ++ch) {
        int krow = st * 16 + lm;
        int byo = (krow * 256 + ch * 64 + lg * 16) ^ ((krow & 7) << 4);
        f16x8 kf = *(const f16x8*)(Bc + byo);
        c = __builtin_amdgcn_mfma_f32_16x16x32_f16(qf[ch], kf, c, 0, 0, 0);
      }
      sf[st] = c;
    }
    __builtin_amdgcn_s_setprio(0);

    // ---- mask + online softmax with defer-rescale (THR=8) ----
    float sc[4][4];   // [r][st]
    float mx4[4];
#pragma unroll
    for (int r = 0; r < 4; ++r) {
      float mx = -1e30f;
#pragma unroll
      for (int st = 0; st < 4; ++st) {
        float s = sf[st][r];
        s = mk[r][st] ? s : -1e-9f;
        sc[r][st] = s;
        mx = fmaxf(mx, s);
      }
      mx = fmaxf(mx, __shfl_xor(mx, 1));
      mx = fmaxf(mx, __shfl_xor(mx, 2));
      mx = fmaxf(mx, __shfl_xor(mx, 4));
      mx = fmaxf(mx, __shfl_xor(mx, 8));
      mx4[r] = mx;
    }
    bool need = false;
#pragma unroll
    for (int r = 0; r < 4; ++r) need = need || (mx4[r] > mrun[r] + 8.f);
    if (__any(need)) {
#pragma unroll
      for (int r = 0; r < 4; ++r) {
        float mnew = fmaxf(mrun[r], mx4[r]);
        float scale = __expf(mrun[r] - mnew);
        lrun[r] *= scale;
        mrun[r] = mnew;
#pragma unroll
        for (int dt = 0; dt < 8; ++dt) acc[dt][r] *= scale;
      }
    }
    float pv[4][4];   // [st][r]
#pragma unroll
    for (int r = 0; r < 4; ++r) {
      float ps = 0.f;
#pragma unroll
      for (int st = 0; st < 4; ++st) {
        float p = __expf(sc[r][st] - mrun[r]);   // bounded by e^8
        pv[st][r] = p;
        ps += p;
      }
      ps += __shfl_xor(ps, 1);
      ps += __shfl_xor(ps, 2);
      ps += __shfl_xor(ps, 4);
      ps += __shfl_xor(ps, 8);
      lrun[r] += ps;
    }

    // ---- P -> wave-private LDS, [16][64] f16 swizzled ----
#pragma unroll
    for (int st = 0; st < 4; ++st) {
#pragma unroll
      for (int r = 0; r < 4; ++r) {
        int row = lg * 4 + r;
        int byo = (row * 128 + (st * 16 + lm) * 2) ^ ((row & 7) << 4);
        *(short*)(Pw + byo) = f2h(pv[st][r]);
      }
    }
    asm volatile("s_waitcnt lgkmcnt(0)" ::: "memory");
    __builtin_amdgcn_sched_barrier(0);

    // ---- PV: O(16x128) += P(16x64) * V(64x128) ----
    __builtin_amdgcn_s_setprio(1);
#pragma unroll
    for (int kk = 0; kk < 2; ++kk) {
      f16x8 pa = *(const f16x8*)(Pw + ((lm * 128 + kk * 64 + lg * 16) ^ ((lm & 7) << 4)));
#pragma unroll
      for (int dt = 0; dt < 8; ++dt) {
        int vrow = dt * 16 + lm;
        f16x8 vb = *(const f16x8*)(Bc + 16384 + ((vrow * 128 + kk * 64 + lg * 16) ^ ((lm & 7) << 4)));
        acc[dt] = __builtin_amdgcn_mfma_f32_16x16x32_f16(pa, vb, acc[dt], 0, 0, 0);
      }
    }
    __builtin_amdgcn_s_setprio(0);

    __builtin_amdgcn_sched_barrier(0);
    __builtin_amdgcn_s_barrier();   // all waves done with buf[cur] before restage

    if (kt + 1 < NKT) {
#pragma unroll
      for (int r = 0; r < 4; ++r)
#pragma unroll
        for (int st = 0; st < 4; ++st) mk[r][st] = mkn[r][st];
    }
  }

  // ---- epilogue ----
  float invl[4];
#pragma unroll
  for (int r = 0; r < 4; ++r) invl[r] = 1.f / lrun[r];
  float* ob = Og + base;
#pragma unroll
  for (int dt = 0; dt < 8; ++dt) {
#pragma unroll
    for (int r = 0; r < 4; ++r) {
      ob[(size_t)(qrow0 + lg * 4 + r) * HD + dt * 16 + lm] = acc[dt][r] * invl[r];
    }
  }
}

// ============================================================================
// Fallback (Round-3 verified bf16 hi/lo kernel) if ws too small for images.
// ============================================================================
typedef __attribute__((ext_vector_type(8))) short bf16x8;
#define KSM_BYTES (KVBLK * HD * 2)
#define VSM_BYTES (HD * 72 * 2)
#define PSM_PER_WAVE (16 * 72 * 2)
#define SMEM_BYTES (2 * KSM_BYTES + VSM_BYTES + 8 * PSM_PER_WAVE)

__global__ __launch_bounds__(TPB, 2) void attn_fwd(
    const float* __restrict__ Kg, const float* __restrict__ Vg,
    const float* __restrict__ Qg, const int* __restrict__ Mg,
    float* __restrict__ Og) {
  __shared__ __align__(16) char smem[SMEM_BYTES];
  char* KsmH = smem;
  char* KsmL = smem + KSM_BYTES;
  char* Vsm = smem + 2 * KSM_BYTES;
  char* Psm = smem + 2 * KSM_BYTES + VSM_BYTES;

  const int tid = threadIdx.x;
  const int wave = tid >> 6;
  const int lane = tid & 63;
  const int lm = lane & 15;
  const int lg = lane >> 4;

  const int bh = blockIdx.x;
  const int q0 = blockIdx.y * QBLK;
  const int qrow0 = q0 + wave * 16;

  const size_t base = (size_t)bh * S_LEN * HD;
  const float* Kb = Kg + base;
  const float* Vb = Vg + base;
  const float* Qb = Qg + base;

  bf16x8 qhi[4], qlo[4];
#pragma unroll
  for (int c = 0; c < 4; ++c) {
    const float* src = Qb + (size_t)(qrow0 + lm) * HD + c * 32 + lg * 8;
    float4 a = *(const float4*)src;
    float4 b = *(const float4*)(src + 4);
    float qs[8] = {a.x, a.y, a.z, a.w, b.x, b.y, b.z, b.w};
    bf16x8 fh, fl;
#pragma unroll
    for (int j = 0; j < 8; ++j) {
      float v = qs[j] * 1.25f;
      unsigned short h = f2b(v);
      fh[j] = (short)h;
      fl[j] = (short)f2b(v - b2f(h));
    }
    qhi[c] = fh;
    qlo[c] = fl;
  }

  f32x4 acc[8];
#pragma unroll
  for (int i = 0; i < 8; ++i) acc[i] = (f32x4){0.f, 0.f, 0.f, 0.f};
  float mrun[4] = {-1e30f, -1e30f, -1e30f, -1e30f};
  float lrun[4] = {0.f, 0.f, 0.f, 0.f};

  char* Pw = Psm + wave * PSM_PER_WAVE;

  for (int kt = 0; kt < S_LEN / KVBLK; ++kt) {
    const int kv0 = kt * KVBLK;
    int mk[4][4];
#pragma unroll
    for (int r = 0; r < 4; ++r) {
      const int* mr = Mg + (size_t)(qrow0 + lg * 4 + r) * S_LEN + kv0 + lm;
#pragma unroll
      for (int st = 0; st < 4; ++st) mk[r][st] = mr[st * 16];
    }
    __syncthreads();
#pragma unroll
    for (int it = 0; it < 4; ++it) {
      int row = it * 16 + (tid >> 5);
      int col = (tid & 31) * 4;
      float4 v = *(const float4*)(Kb + (size_t)(kv0 + row) * HD + col);
      ushort4 hi, lo;
      hi.x = f2b(v.x); lo.x = f2b(v.x - b2f(hi.x));
      hi.y = f2b(v.y); lo.y = f2b(v.y - b2f(hi.y));
      hi.z = f2b(v.z); lo.z = f2b(v.z - b2f(hi.z));
      hi.w = f2b(v.w); lo.w = f2b(v.w - b2f(hi.w));
      int byo = (row * 256 + col * 2) ^ ((row & 7) << 4);
      *(ushort4*)(KsmH + byo) = hi;
      *(ushort4*)(KsmL + byo) = lo;
    }
    {
      int d = tid & 127;
      int kvh = (tid >> 7) * 16;
      const float* vc = Vb + (size_t)kv0 * HD + d;
#pragma unroll
      for (int j = 0; j < 4; ++j) {
        int kvb = kvh + j * 4;
        ushort4 h = make_ushort4(f2b(vc[(size_t)(kvb + 0) * HD]),
                                 f2b(vc[(size_t)(kvb + 1) * HD]),
                                 f2b(vc[(size_t)(kvb + 2) * HD]),
                                 f2b(vc[(size_t)(kvb + 3) * HD]));
        *(ushort4*)(Vsm + d * 144 + kvb * 2) = h;
      }
    }
    __syncthreads();

    f32x4 sf[4];
#pragma unroll
    for (int st = 0; st < 4; ++st) {
      f32x4 c = (f32x4){0.f, 0.f, 0.f, 0.f};
#pragma unroll
      for (int ch = 0; ch < 4; ++ch) {
        int krow = st * 16 + lm;
        int byo = (krow * 256 + (ch * 32 + lg * 8) * 2) ^ ((krow & 7) << 4);
        bf16x8 khi = *(const bf16x8*)(KsmH + byo);
        bf16x8 klo = *(const bf16x8*)(KsmL + byo);
        c = __builtin_amdgcn_mfma_f32_16x16x32_bf16(qhi[ch], khi, c, 0, 0, 0);
        c = __builtin_amdgcn_mfma_f32_16x16x32_bf16(qlo[ch], khi, c, 0, 0, 0);
        c = __builtin_amdgcn_mfma_f32_16x16x32_bf16(qhi[ch], klo, c, 0, 0, 0);
      }
      sf[st] = c;
    }

    float pv[4][4];
#pragma unroll
    for (int r = 0; r < 4; ++r) {
      float sc[4];
      float mx = -1e30f;
#pragma unroll
      for (int st = 0; st < 4; ++st) {
        float s = sf[st][r];
        sc[st] = mk[r][st] ? s : -1e-9f;
        mx = fmaxf(mx, sc[st]);
      }
      mx = fmaxf(mx, __shfl_xor(mx, 1));
      mx = fmaxf(mx, __shfl_xor(mx, 2));
      mx = fmaxf(mx, __shfl_xor(mx, 4));
      mx = fmaxf(mx, __shfl_xor(mx, 8));
      float mnew = fmaxf(mrun[r], mx);
      float scale = __expf(mrun[r] - mnew);
      float ps = 0.f;
#pragma unroll
      for (int st = 0; st < 4; ++st) {
        float p = __expf(sc[st] - mnew);
        pv[st][r] = p;
        ps += p;
      }
      ps += __shfl_xor(ps, 1);
      ps += __shfl_xor(ps, 2);
      ps += __shfl_xor(ps, 4);
      ps += __shfl_xor(ps, 8);
      lrun[r] = lrun[r] * scale + ps;
      mrun[r] = mnew;
#pragma unroll
      for (int dt = 0; dt < 8; ++dt) acc[dt][r] *= scale;
    }

#pragma unroll
    for (int st = 0; st < 4; ++st) {
#pragma unroll
      for (int r = 0; r < 4; ++r) {
        int row = lg * 4 + r;
        int col = st * 16 + lm;
        *(unsigned short*)(Pw + row * 144 + col * 2) = f2b(pv[st][r]);
      }
    }
    asm volatile("s_waitcnt lgkmcnt(0)" ::: "memory");
    __builtin_amdgcn_sched_barrier(0);

#pragma unroll
    for (int kk = 0; kk < 2; ++kk) {
      bf16x8 pa = *(const bf16x8*)(Pw + lm * 144 + kk * 64 + lg * 16);
#pragma unroll
      for (int dt = 0; dt < 8; ++dt) {
        bf16x8 vb = *(const bf16x8*)(Vsm + (dt * 16 + lm) * 144 + kk * 64 + lg * 16);
        acc[dt] = __builtin_amdgcn_mfma_f32_16x16x32_bf16(pa, vb, acc[dt], 0, 0, 0);
      }
    }
  }

  float invl[4];
#pragma unroll
  for (int r = 0; r < 4; ++r) invl[r] = 1.f / lrun[r];
  float* ob = Og + base;
#pragma unroll
  for (int dt = 0; dt < 8; ++dt) {
#pragma unroll
    for (int r = 0; r < 4; ++r) {
      ob[(size_t)(qrow0 + lg * 4 + r) * HD + dt * 16 + lm] = acc[dt][r] * invl[r];
    }
  }
}

extern "C" void kernel_launch(void* const* d_in, const int* in_sizes, int n_in,
                              void* d_out, int out_size, void* d_ws, size_t ws_size,
                              hipStream_t stream) {
  const float* key   = (const float*)d_in[0];
  const float* value = (const float*)d_in[1];
  const float* query = (const float*)d_in[2];
  const int*   mask  = (const int*)d_in[3];
  float* out = (float*)d_out;

  const size_t PLANE = (size_t)NBH * NKT * KIMG_TILE;  // 16MB
  if (ws_size >= 2 * PLANE) {
    char* kf = (char*)d_ws;
    char* vt = kf + PLANE;
    prep_kv<<<dim3(NBH * NKT), dim3(256), 0, stream>>>(key, value, kf, vt);
    attn_fwd4<<<dim3(NBH, S_LEN / QBLK), dim3(TPB), 0, stream>>>(kf, vt, query, mask, out);
  } else {
    attn_fwd<<<dim3(NBH, S_LEN / QBLK), dim3(TPB), 0, stream>>>(key, value, query, mask, out);
  }
}